// Round 16
// baseline (14.218 us; speedup 1.0000x reference)
//
#include <hip/hip_runtime.h>
#include <limits.h>

// BKT: B=4096 students, T=512 timesteps, K=2048 skills.
// R16 = R15 + two changes driven by the barrier-drain mechanism
// (__syncthreads emits s_waitcnt vmcnt(0) before s_barrier -> any
// outstanding scattered gather serializes INTO the prologue):
//  1. k0[sk] gathers moved AFTER the last barrier, issued right before the
//     dependent walk (~700cy) that hides their latency. Explains R11's
//     regression (more pre-barrier gathers = longer drain) and R6's win
//     (lazy gathers never cross a barrier).
//  2. adjacent-timestep ownership (t = 2*tid, 2*tid+1): skills/resp load as
//     int2/float2, out stores as float2 -> half the global instrs to drain.
// Kept from R15: dual interleaved chain walk (2 ds_reads in flight),
// min1/min2 capture (rescan only rank>=3), direct 2048 head table, lazy
// t/g/s, 2 barriers, LDS 10KB, launch_bounds(256,8) = 32 waves/CU.

#define BKT_B 4096
#define BKT_T 512
#define BKT_K 2048
#define BLK   256
#define PTR_END 0x3FF

__device__ __forceinline__ float bkt_update(float p, int rbit, float ss,
                                            float gg, float tt) {
  float num, den;
  if (rbit) {                // correct response
    num = p * (1.0f - ss);
    den = num + (1.0f - p) * gg;
  } else {                   // incorrect response
    num = p * ss;
    den = num + (1.0f - p) * (1.0f - gg);
  }
  const float q = num / den; // Bayesian posterior
  return q + (1.0f - q) * tt;// learning transition
}

__global__ __launch_bounds__(BLK, 8) void bkt_kernel(
    const int* __restrict__ skills,
    const float* __restrict__ resp,
    const float* __restrict__ k0,
    const float* __restrict__ tp,
    const float* __restrict__ gp,
    const float* __restrict__ sp,
    float* __restrict__ out) {
  __shared__ int head_s[BKT_K];  // 8KB direct-mapped: last arrival, -1 empty
  __shared__ int node_s[BKT_T];  // 2KB packed {resp bit, prev ptr}

  const int b = blockIdx.x;
  const int base = b * BKT_T;
  const int tid = threadIdx.x;
  const int t0 = 2 * tid;
  const int t1 = 2 * tid + 1;

  // one int2 + one float2 coalesced load for this thread's two timesteps
  const int2   skv = ((const int2*)(skills + base))[tid];
  const float2 rrv = ((const float2*)(resp + base))[tid];
  const int sk0 = skv.x, sk1 = skv.y;

  // head init: 2048 ints = two int4 stores per thread
  {
    int4* h4 = (int4*)head_s;
    h4[tid] = make_int4(-1, -1, -1, -1);
    h4[tid + BLK] = make_int4(-1, -1, -1, -1);
  }
  __syncthreads();

  // build per-skill linked lists (arrival order arbitrary)
  {
    const int old0 = atomicExch(&head_s[sk0], t0);
    node_s[t0] = ((old0 < 0) ? PTR_END : old0) | ((rrv.x > 0.5f ? 1 : 0) << 10);
    const int old1 = atomicExch(&head_s[sk1], t1);
    node_s[t1] = ((old1 < 0) ? PTR_END : old1) | ((rrv.y > 0.5f ? 1 : 0) << 10);
  }
  __syncthreads();

  // k0 gathers issued NOW (after all barriers): latency hides under the walk
  const float k00 = k0[sk0];
  const float k01 = k0[sk1];

  // dual-chain interleaved walk: both timesteps' chains advance together
  const int head0 = head_s[sk0];
  const int head1 = head_s[sk1];
  int j0 = head0, j1 = head1;
  int rank0 = 0, rank1 = 0;
  int a0 = INT_MAX, b0 = INT_MAX, an0 = 0, bn0 = 0;  // min1/min2 (t0)
  int a1 = INT_MAX, b1 = INT_MAX, an1 = 0, bn1 = 0;  // min1/min2 (t1)
  while ((j0 >= 0) || (j1 >= 0)) {
    if (j0 >= 0) {
      const int nd = node_s[j0];
      if (j0 < t0) {
        ++rank0;
        if (j0 < a0)      { b0 = a0; bn0 = an0; a0 = j0; an0 = nd; }
        else if (j0 < b0) { b0 = j0; bn0 = nd; }
      }
      const int nx = nd & PTR_END;
      j0 = (nx == PTR_END) ? -1 : nx;
    }
    if (j1 >= 0) {
      const int nd = node_s[j1];
      if (j1 < t1) {
        ++rank1;
        if (j1 < a1)      { b1 = a1; bn1 = an1; a1 = j1; an1 = nd; }
        else if (j1 < b1) { b1 = j1; bn1 = nd; }
      }
      const int nx = nd & PTR_END;
      j1 = (nx == PTR_END) ? -1 : nx;
    }
  }

  // ---- t0 replay ----
  float p0 = k00;
  if (rank0 > 0) {
    const float ss = sp[sk0];
    const float gg = gp[sk0];
    const float tt = tp[sk0];
    p0 = bkt_update(p0, (an0 >> 10) & 1, ss, gg, tt);
    if (rank0 > 1) {
      p0 = bkt_update(p0, (bn0 >> 10) & 1, ss, gg, tt);
      int cur = b0;
      for (int rd = 2; rd < rank0; ++rd) {   // rank>=3 only (~0.3% lanes)
        int best = INT_MAX, bestnode = 0;
        for (int j = head0; j >= 0; ) {
          const int nd = node_s[j];
          if (j < t0 && j > cur && j < best) { best = j; bestnode = nd; }
          const int nx = nd & PTR_END;
          j = (nx == PTR_END) ? -1 : nx;
        }
        p0 = bkt_update(p0, (bestnode >> 10) & 1, ss, gg, tt);
        cur = best;
      }
    }
  }

  // ---- t1 replay ----
  float p1 = k01;
  if (rank1 > 0) {
    const float ss = sp[sk1];
    const float gg = gp[sk1];
    const float tt = tp[sk1];
    p1 = bkt_update(p1, (an1 >> 10) & 1, ss, gg, tt);
    if (rank1 > 1) {
      p1 = bkt_update(p1, (bn1 >> 10) & 1, ss, gg, tt);
      int cur = b1;
      for (int rd = 2; rd < rank1; ++rd) {
        int best = INT_MAX, bestnode = 0;
        for (int j = head1; j >= 0; ) {
          const int nd = node_s[j];
          if (j < t1 && j > cur && j < best) { best = j; bestnode = nd; }
          const int nx = nd & PTR_END;
          j = (nx == PTR_END) ? -1 : nx;
        }
        p1 = bkt_update(p1, (bestnode >> 10) & 1, ss, gg, tt);
        cur = best;
      }
    }
  }

  // one float2 coalesced store
  ((float2*)(out + base))[tid] = make_float2(p0, p1);
}

extern "C" void kernel_launch(void* const* d_in, const int* in_sizes, int n_in,
                              void* d_out, int out_size, void* d_ws, size_t ws_size,
                              hipStream_t stream) {
  const int*   skills = (const int*)d_in[0];
  const float* resp   = (const float*)d_in[1];
  const float* k0     = (const float*)d_in[2];
  const float* tp     = (const float*)d_in[3];
  const float* gp     = (const float*)d_in[4];
  const float* sp     = (const float*)d_in[5];
  float* out = (float*)d_out;

  bkt_kernel<<<BKT_B, BLK, 0, stream>>>(skills, resp, k0, tp, gp, sp, out);
}